// Round 1
// baseline (729.560 us; speedup 1.0000x reference)
//
#include <hip/hip_runtime.h>
#include <hip/hip_bf16.h>
#include <math.h>

typedef unsigned short u16;
typedef unsigned int   u32;
typedef unsigned char  u8;

#define NB  128
#define NLT 64
#define NLC 400
#define NL  464
#define ND  768
#define NH  3072
#define NEGF (-1e20f)

__device__ __forceinline__ float b2f(u16 u){ return __uint_as_float(((u32)u)<<16); }
__device__ __forceinline__ u16 f2b(float f){
  u32 x = __float_as_uint(f);
  x += 0x7fffu + ((x>>16)&1u);
  return (u16)(x>>16);
}
template<bool BF> __device__ __forceinline__ float ldf(const void* p, size_t i){
  if constexpr (BF) return b2f(((const u16*)p)[i]);
  else              return ((const float*)p)[i];
}

// ---------------------------------------------------------------- ABI detect
// flags[0]: 1 if float tensors are bf16, 0 if float32
// flags[1]: 1 if masks are 1-byte (bool), 0 if int32
__global__ void k_detect(const void* tem, const void* tmask, int* flags){
  if (threadIdx.x == 0){
    const u16* p = (const u16*)tem;
    float acc = 0.f;
    for (int i = 0; i < 512; i++){
      float v = fabsf(b2f(p[i]));
      v = fminf(v, 1e10f);            // NaN -> 1e10 via fminf, inf clamped
      acc += v;
    }
    flags[0] = (acc < 1e4f) ? 1 : 0;  // bf16 data: acc ~ 4e2; f32-as-bf16: huge
    const u8* mb = (const u8*)tmask;
    int nz = 0;
    for (int i = 0; i < 400; i++) if ((i & 3) != 0 && mb[i] != 0) nz++;
    flags[1] = (nz > 0) ? 1 : 0;      // int32 masks have zero bytes off 4-boundary
  }
}

// ---------------------------------------------------------------- sim logits
template<bool BF>
__device__ void sim_body(const void* tem, const void* ctx, const void* cls,
                         const void* lsp, float* sim,
                         float* clsf, float* red4, float* cnorm)
{
  int b = blockIdx.x, tile = blockIdx.y, tid = threadIdx.x;
  for (int i = tid; i < ND; i += 256) clsf[i] = ldf<BF>(cls, (size_t)b*ND + i);
  __syncthreads();
  float ss = 0.f;
  for (int i = tid; i < ND; i += 256) ss += clsf[i]*clsf[i];
  for (int off = 32; off; off >>= 1) ss += __shfl_down(ss, off);
  if ((tid & 63) == 0) red4[tid >> 6] = ss;
  __syncthreads();
  if (tid == 0) *cnorm = fmaxf(sqrtf(red4[0]+red4[1]+red4[2]+red4[3]), 1e-12f);
  __syncthreads();
  float cn = *cnorm;
  float escale = expf(ldf<BF>(lsp, 0));
  int lane = tid & 63, w = tid >> 6;
  float creg[12];
  #pragma unroll
  for (int j = 0; j < 12; j++) creg[j] = clsf[lane*12 + j];

  for (int rr = 0; rr < 4; rr++){
    int l = tile*16 + w + rr*4;
    float v[12];
    if constexpr (BF){
      const u16* row = (l < NLT) ? ((const u16*)tem + ((size_t)b*NLT + l)*ND)
                                 : ((const u16*)ctx + ((size_t)b*NLC + (l-NLT))*ND);
      const ushort4* rp = (const ushort4*)(row + lane*12);
      #pragma unroll
      for (int q = 0; q < 3; q++){
        ushort4 u = rp[q];
        v[q*4+0]=b2f(u.x); v[q*4+1]=b2f(u.y); v[q*4+2]=b2f(u.z); v[q*4+3]=b2f(u.w);
      }
    } else {
      const float* row = (l < NLT) ? ((const float*)tem + ((size_t)b*NLT + l)*ND)
                                   : ((const float*)ctx + ((size_t)b*NLC + (l-NLT))*ND);
      const float4* rp = (const float4*)(row + lane*12);
      #pragma unroll
      for (int q = 0; q < 3; q++){
        float4 u = rp[q];
        v[q*4+0]=u.x; v[q*4+1]=u.y; v[q*4+2]=u.z; v[q*4+3]=u.w;
      }
    }
    float dot = 0.f, rs = 0.f;
    #pragma unroll
    for (int j = 0; j < 12; j++){ dot += creg[j]*v[j]; rs += v[j]*v[j]; }
    for (int off = 32; off; off >>= 1){
      dot += __shfl_down(dot, off); rs += __shfl_down(rs, off);
    }
    if (lane == 0){
      float rn = fmaxf(sqrtf(rs), 1e-12f);
      sim[(size_t)b*NL + l] = dot / (cn*rn) * escale;
    }
  }
}
__global__ __launch_bounds__(256) void k_sim(const int* flags, const void* tem,
    const void* ctx, const void* cls, const void* lsp, float* sim){
  __shared__ float clsf[ND];
  __shared__ float red4[4];
  __shared__ float cnorm;
  if (flags[0]) sim_body<true >(tem, ctx, cls, lsp, sim, clsf, red4, &cnorm);
  else          sim_body<false>(tem, ctx, cls, lsp, sim, clsf, red4, &cnorm);
}

// ---------------------------------------------------------------- reductions
__device__ __forceinline__ float bred_max(float v, float* red, int tid){
  red[tid] = v; __syncthreads();
  for (int s = 256; s > 0; s >>= 1){ if (tid < s) red[tid] = fmaxf(red[tid], red[tid+s]); __syncthreads(); }
  float r = red[0]; __syncthreads(); return r;
}
__device__ __forceinline__ float bred_min(float v, float* red, int tid){
  red[tid] = v; __syncthreads();
  for (int s = 256; s > 0; s >>= 1){ if (tid < s) red[tid] = fminf(red[tid], red[tid+s]); __syncthreads(); }
  float r = red[0]; __syncthreads(); return r;
}
__device__ __forceinline__ float bred_sum(float v, float* red, int tid){
  red[tid] = v; __syncthreads();
  for (int s = 256; s > 0; s >>= 1){ if (tid < s) red[tid] += red[tid+s]; __syncthreads(); }
  float r = red[0]; __syncthreads(); return r;
}

// ---------------------------------------------------------------- scores
template<bool M8>
__device__ void scores_body(const float* sim, const void* tmask, const void* cmask,
                            float* tgts, float* diss, float* bgds,
                            float* srt, float* cum, float* red)
{
  int b = blockIdx.x, tid = threadIdx.x;
  bool valid = tid < NL;
  float sv = valid ? sim[(size_t)b*NL + tid] : 0.f;
  bool mk = false;
  if (valid){
    if constexpr (M8)
      mk = (tid < NLT) ? (((const u8*)tmask)[b*NLT + tid] != 0)
                       : (((const u8*)cmask)[b*NLC + tid - NLT] != 0);
    else
      mk = (tid < NLT) ? (((const int*)tmask)[b*NLT + tid] != 0)
                       : (((const int*)cmask)[b*NLC + tid - NLT] != 0);
  }
  // tgt softmax: keep where mask True
  float lt = (valid && mk) ? sv : NEGF;
  float m1 = bred_max(lt, red, tid);
  float e1 = valid ? expf(lt - m1) : 0.f;
  float s1 = bred_sum(e1, red, tid);
  if (valid) tgts[(size_t)b*NL + tid] = e1/s1;

  // background logits: keep where mask False
  float bl = (valid && !mk) ? sv : NEGF;
  float m2 = bred_max(bl, red, tid);
  float e2 = valid ? expf(bl - m2) : 0.f;
  float s2 = bred_sum(e2, red, tid);
  float bg0 = e2/s2;

  // sort ascending (pads -> +inf at top)
  srt[tid] = valid ? bg0 : INFINITY;
  __syncthreads();
  for (int k = 2; k <= 512; k <<= 1){
    for (int j = k >> 1; j > 0; j >>= 1){
      int ixj = tid ^ j;
      if (ixj > tid){
        float a = srt[tid], c = srt[ixj];
        if ((a > c) == ((tid & k) == 0)){ srt[tid] = c; srt[ixj] = a; }
      }
      __syncthreads();
    }
  }
  // inclusive scan
  cum[tid] = srt[tid]; __syncthreads();
  for (int off = 1; off < 512; off <<= 1){
    float t = (tid >= off) ? cum[tid - off] : 0.f;
    __syncthreads();
    cum[tid] += t;
    __syncthreads();
  }
  float cand = (cum[tid] < 0.25f) ? 1.0f : srt[tid];
  float thr = bred_min(cand, red, tid);

  bool dm = valid && (bg0 >= thr);
  float dl = dm ? bl : NEGF;         // distractor logits
  float l2 = dm ? NEGF : bl;         // remaining background logits
  float m3 = bred_max(dl, red, tid);
  float e3 = valid ? expf(dl - m3) : 0.f;
  float s3 = bred_sum(e3, red, tid);
  if (valid) diss[(size_t)b*NL + tid] = e3/s3;
  float m4 = bred_max(l2, red, tid);
  float e4 = valid ? expf(l2 - m4) : 0.f;
  float s4 = bred_sum(e4, red, tid);
  if (valid) bgds[(size_t)b*NL + tid] = e4/s4;
}
__global__ __launch_bounds__(512) void k_scores(const int* flags, const float* sim,
    const void* tmask, const void* cmask, float* tgts, float* diss, float* bgds){
  __shared__ float srt[512];
  __shared__ float cum[512];
  __shared__ float red[512];
  if (flags[1]) scores_body<true >(sim, tmask, cmask, tgts, diss, bgds, srt, cum, red);
  else          scores_body<false>(sim, tmask, cmask, tgts, diss, bgds, srt, cum, red);
}

// ---------------------------------------------------------------- tokens + src0
template<bool BF>
__device__ void tokens_body(const void* tem, const void* ctx, const void* cls, const void* qe,
                            const float* tgts, const float* diss, const float* bgds,
                            float* src0, float* s0, float* s1, float* s2)
{
  int b = blockIdx.x, t = threadIdx.x;
  for (int i = t; i < NL; i += 384){
    s0[i] = tgts[(size_t)b*NL + i];
    s1[i] = diss[(size_t)b*NL + i];
    s2[i] = bgds[(size_t)b*NL + i];
  }
  __syncthreads();
  float a00=0,a01=0,a10=0,a11=0,a20=0,a21=0;
  for (int l = 0; l < NL; l++){
    float f0, f1;
    if constexpr (BF){
      const u16* row = (l < NLT) ? ((const u16*)tem + ((size_t)b*NLT + l)*ND)
                                 : ((const u16*)ctx + ((size_t)b*NLC + (l-NLT))*ND);
      u32 v = ((const u32*)row)[t];
      f0 = b2f((u16)(v & 0xffff)); f1 = b2f((u16)(v >> 16));
    } else {
      const float* row = (l < NLT) ? ((const float*)tem + ((size_t)b*NLT + l)*ND)
                                   : ((const float*)ctx + ((size_t)b*NLC + (l-NLT))*ND);
      float2 v = ((const float2*)row)[t];
      f0 = v.x; f1 = v.y;
    }
    float w0 = s0[l], w1 = s1[l], w2 = s2[l];
    a00 += w0*f0; a01 += w0*f1;
    a10 += w1*f0; a11 += w1*f1;
    a20 += w2*f0; a21 += w2*f1;
  }
  int d0 = t*2, d1 = d0 + 1;
  float c0 = ldf<BF>(cls, (size_t)b*ND + d0), c1 = ldf<BF>(cls, (size_t)b*ND + d1);
  size_t base = (size_t)b*3*ND;
  src0[base       + d0] = a00 + ldf<BF>(qe, 0*ND + d0) + c0;
  src0[base       + d1] = a01 + ldf<BF>(qe, 0*ND + d1) + c1;
  src0[base +   ND + d0] = a10 + ldf<BF>(qe, 1*ND + d0);
  src0[base +   ND + d1] = a11 + ldf<BF>(qe, 1*ND + d1);
  src0[base + 2*ND + d0] = a20 + ldf<BF>(qe, 2*ND + d0);
  src0[base + 2*ND + d1] = a21 + ldf<BF>(qe, 2*ND + d1);
}
__global__ __launch_bounds__(384) void k_tokens(const int* flags, const void* tem,
    const void* ctx, const void* cls, const void* qe,
    const float* tgts, const float* diss, const float* bgds, float* src0){
  __shared__ float s0[NL], s1[NL], s2[NL];
  if (flags[0]) tokens_body<true >(tem, ctx, cls, qe, tgts, diss, bgds, src0, s0, s1, s2);
  else          tokens_body<false>(tem, ctx, cls, qe, tgts, diss, bgds, src0, s0, s1, s2);
}

// ---------------------------------------------------------------- fc1 + gelu
template<bool BF>
__device__ void fc1_body(const float* src0, const void* w1, const void* b1, float* h,
                         float (*As)[33], float (*Bs)[65])
{
  int tid = threadIdx.x;
  int n0 = blockIdx.x*64, m0 = blockIdx.y*32;
  int c = tid & 63, rg = tid >> 6;
  float acc[8] = {0,0,0,0,0,0,0,0};
  for (int k0 = 0; k0 < ND; k0 += 32){
    #pragma unroll
    for (int q = 0; q < 4; q++){
      int e = tid + q*256, r = e >> 5, cc = e & 31;
      As[r][cc] = src0[(size_t)(m0+r)*ND + k0 + cc];
    }
    #pragma unroll
    for (int q = 0; q < 8; q++){
      int e = tid + q*256, kr = e >> 6, cc = e & 63;
      Bs[kr][cc] = ldf<BF>(w1, (size_t)(k0+kr)*NH + n0 + cc);
    }
    __syncthreads();
    #pragma unroll
    for (int kk = 0; kk < 32; kk++){
      float bv = Bs[kk][c];
      #pragma unroll
      for (int i = 0; i < 8; i++) acc[i] += As[rg + i*4][kk] * bv;
    }
    __syncthreads();
  }
  float bb = ldf<BF>(b1, n0 + c);
  #pragma unroll
  for (int i = 0; i < 8; i++){
    float x = acc[i] + bb;
    h[(size_t)(m0 + rg + i*4)*NH + n0 + c] = 0.5f*x*(1.0f + erff(x*0.70710678118654752f));
  }
}
__global__ __launch_bounds__(256) void k_fc1(const int* flags, const float* src0,
    const void* w1, const void* b1, float* h){
  __shared__ float As[32][33];
  __shared__ float Bs[32][65];
  if (flags[0]) fc1_body<true >(src0, w1, b1, h, As, Bs);
  else          fc1_body<false>(src0, w1, b1, h, As, Bs);
}

// ---------------------------------------------------------------- fc2 + epilogue
template<bool BF>
__device__ void fc2_body(const float* h, const void* w2, const void* b2p,
                         const float* src0, const void* cls, const void* qe,
                         const int* flag, void* out,
                         float (*As)[33], float (*Bs)[65])
{
  int tid = threadIdx.x;
  int n0 = blockIdx.x*64, m0 = blockIdx.y*16;
  int c = tid & 63, rg = tid >> 6;
  float acc[4] = {0,0,0,0};
  for (int k0 = 0; k0 < NH; k0 += 32){
    #pragma unroll
    for (int q = 0; q < 2; q++){
      int e = tid + q*256, r = e >> 5, cc = e & 31;
      As[r][cc] = h[(size_t)(m0+r)*NH + k0 + cc];
    }
    #pragma unroll
    for (int q = 0; q < 8; q++){
      int e = tid + q*256, kr = e >> 6, cc = e & 63;
      Bs[kr][cc] = ldf<BF>(w2, (size_t)(k0+kr)*ND + n0 + cc);
    }
    __syncthreads();
    #pragma unroll
    for (int kk = 0; kk < 32; kk++){
      float bv = Bs[kk][c];
      #pragma unroll
      for (int i = 0; i < 4; i++) acc[i] += As[rg + i*4][kk] * bv;
    }
    __syncthreads();
  }
  float bb = ldf<BF>(b2p, n0 + c);
  #pragma unroll
  for (int i = 0; i < 4; i++){
    int r = m0 + rg + i*4;
    int bi = r/3, j = r - bi*3;
    int n = n0 + c;
    float val = acc[i] + bb + src0[(size_t)r*ND + n];
    if (flag[bi] == 1){
      val = ldf<BF>(qe, (size_t)j*ND + n) + ((j == 0) ? ldf<BF>(cls, (size_t)bi*ND + n) : 0.f);
    }
    if constexpr (BF) ((u16*)out)[(size_t)r*ND + n] = f2b(val);
    else              ((float*)out)[(size_t)r*ND + n] = val;
  }
}
__global__ __launch_bounds__(256) void k_fc2(const int* flags, const float* h,
    const void* w2, const void* b2p, const float* src0, const void* cls,
    const void* qe, const int* flag, void* out){
  __shared__ float As[16][33];
  __shared__ float Bs[32][65];
  if (flags[0]) fc2_body<true >(h, w2, b2p, src0, cls, qe, flag, out, As, Bs);
  else          fc2_body<false>(h, w2, b2p, src0, cls, qe, flag, out, As, Bs);
}

// ---------------------------------------------------------------- launch
extern "C" void kernel_launch(void* const* d_in, const int* in_sizes, int n_in,
                              void* d_out, int out_size, void* d_ws, size_t ws_size,
                              hipStream_t stream)
{
  const void* tem   = d_in[0];
  const void* tmask = d_in[1];
  const void* ctx   = d_in[2];
  const void* cmask = d_in[3];
  const void* cls   = d_in[4];
  const int*  flag  = (const int*)d_in[5];
  const void* qe    = d_in[6];
  const void* ls    = d_in[7];
  const void* w1    = d_in[8];
  const void* b1    = d_in[9];
  const void* w2    = d_in[10];
  const void* b2    = d_in[11];

  int*   flags = (int*)d_ws;
  float* W     = (float*)d_ws + 16;
  float* sim   = W;
  float* tgts  = sim  + (size_t)NB*NL;
  float* diss  = tgts + (size_t)NB*NL;
  float* bgds  = diss + (size_t)NB*NL;
  float* src0  = bgds + (size_t)NB*NL;
  float* h     = src0 + (size_t)NB*3*ND;

  hipLaunchKernelGGL(k_detect, dim3(1), dim3(64), 0, stream, tem, tmask, flags);
  hipLaunchKernelGGL(k_sim,    dim3(NB, 29), dim3(256), 0, stream, flags, tem, ctx, cls, ls, sim);
  hipLaunchKernelGGL(k_scores, dim3(NB), dim3(512), 0, stream, flags, sim, tmask, cmask, tgts, diss, bgds);
  hipLaunchKernelGGL(k_tokens, dim3(NB), dim3(384), 0, stream, flags, tem, ctx, cls, qe, tgts, diss, bgds, src0);
  hipLaunchKernelGGL(k_fc1,    dim3(NH/64, 384/32), dim3(256), 0, stream, flags, src0, w1, b1, h);
  hipLaunchKernelGGL(k_fc2,    dim3(ND/64, 384/16), dim3(256), 0, stream, flags, h, w2, b2, src0, cls, qe, flag, d_out);
}

// Round 2
// 333.324 us; speedup vs baseline: 2.1887x; 2.1887x over previous
//
#include <hip/hip_runtime.h>
#include <hip/hip_bf16.h>
#include <math.h>

typedef unsigned short u16;
typedef unsigned int   u32;
typedef unsigned char  u8;

#define NB  128
#define NLT 64
#define NLC 400
#define NL  464
#define ND  768
#define NH  3072
#define NEGF (-1e20f)

__device__ __forceinline__ float b2f(u16 u){ return __uint_as_float(((u32)u)<<16); }
__device__ __forceinline__ u16 f2b(float f){
  u32 x = __float_as_uint(f);
  x += 0x7fffu + ((x>>16)&1u);
  return (u16)(x>>16);
}
template<bool BF> __device__ __forceinline__ float ldf(const void* p, size_t i){
  if constexpr (BF) return b2f(((const u16*)p)[i]);
  else              return ((const float*)p)[i];
}

// ---------------------------------------------------------------- ABI detect
__global__ void k_detect(const void* tem, const void* tmask, int* flags){
  int t = threadIdx.x;                     // 64 threads
  const u16* p = (const u16*)tem;
  float acc = 0.f;
  for (int i = t; i < 512; i += 64){
    float v = fabsf(b2f(p[i]));
    v = fminf(v, 1e10f);
    acc += v;
  }
  for (int off = 32; off; off >>= 1) acc += __shfl_down(acc, off);
  const u8* mb = (const u8*)tmask;
  int nz = 0;
  for (int i = t; i < 400; i += 64) if ((i & 3) != 0 && mb[i] != 0) nz = 1;
  unsigned long long anym = __ballot(nz);
  if (t == 0){
    flags[0] = (acc < 1e4f) ? 1 : 0;       // bf16 data vs f32-seen-as-bf16
    flags[1] = anym ? 1 : 0;               // byte-mask vs int32-mask
  }
}

// ---------------------------------------------------------------- sim logits
template<bool BF>
__device__ void sim_body(const void* tem, const void* ctx, const void* cls,
                         const void* lsp, float* sim,
                         float* clsf, float* red4, float* cnorm)
{
  int b = blockIdx.x, tile = blockIdx.y, tid = threadIdx.x;
  for (int i = tid; i < ND; i += 256) clsf[i] = ldf<BF>(cls, (size_t)b*ND + i);
  __syncthreads();
  float ss = 0.f;
  for (int i = tid; i < ND; i += 256) ss += clsf[i]*clsf[i];
  for (int off = 32; off; off >>= 1) ss += __shfl_down(ss, off);
  if ((tid & 63) == 0) red4[tid >> 6] = ss;
  __syncthreads();
  if (tid == 0) *cnorm = fmaxf(sqrtf(red4[0]+red4[1]+red4[2]+red4[3]), 1e-12f);
  __syncthreads();
  float cn = *cnorm;
  float escale = expf(ldf<BF>(lsp, 0));
  int lane = tid & 63, w = tid >> 6;
  float creg[12];
  #pragma unroll
  for (int j = 0; j < 12; j++) creg[j] = clsf[lane*12 + j];

  for (int rr = 0; rr < 4; rr++){
    int l = tile*16 + w + rr*4;
    float v[12];
    if constexpr (BF){
      const u16* row = (l < NLT) ? ((const u16*)tem + ((size_t)b*NLT + l)*ND)
                                 : ((const u16*)ctx + ((size_t)b*NLC + (l-NLT))*ND);
      const ushort4* rp = (const ushort4*)(row + lane*12);
      #pragma unroll
      for (int q = 0; q < 3; q++){
        ushort4 u = rp[q];
        v[q*4+0]=b2f(u.x); v[q*4+1]=b2f(u.y); v[q*4+2]=b2f(u.z); v[q*4+3]=b2f(u.w);
      }
    } else {
      const float* row = (l < NLT) ? ((const float*)tem + ((size_t)b*NLT + l)*ND)
                                   : ((const float*)ctx + ((size_t)b*NLC + (l-NLT))*ND);
      const float4* rp = (const float4*)(row + lane*12);
      #pragma unroll
      for (int q = 0; q < 3; q++){
        float4 u = rp[q];
        v[q*4+0]=u.x; v[q*4+1]=u.y; v[q*4+2]=u.z; v[q*4+3]=u.w;
      }
    }
    float dot = 0.f, rs = 0.f;
    #pragma unroll
    for (int j = 0; j < 12; j++){ dot += creg[j]*v[j]; rs += v[j]*v[j]; }
    for (int off = 32; off; off >>= 1){
      dot += __shfl_down(dot, off); rs += __shfl_down(rs, off);
    }
    if (lane == 0){
      float rn = fmaxf(sqrtf(rs), 1e-12f);
      sim[(size_t)b*NL + l] = dot / (cn*rn) * escale;
    }
  }
}
__global__ __launch_bounds__(256) void k_sim(const int* flags, const void* tem,
    const void* ctx, const void* cls, const void* lsp, float* sim){
  __shared__ float clsf[ND];
  __shared__ float red4[4];
  __shared__ float cnorm;
  if (flags[0]) sim_body<true >(tem, ctx, cls, lsp, sim, clsf, red4, &cnorm);
  else          sim_body<false>(tem, ctx, cls, lsp, sim, clsf, red4, &cnorm);
}

// ---------------------------------------------------------------- reductions
__device__ __forceinline__ float bred_max(float v, float* red, int tid){
  red[tid] = v; __syncthreads();
  for (int s = 256; s > 0; s >>= 1){ if (tid < s) red[tid] = fmaxf(red[tid], red[tid+s]); __syncthreads(); }
  float r = red[0]; __syncthreads(); return r;
}
__device__ __forceinline__ float bred_min(float v, float* red, int tid){
  red[tid] = v; __syncthreads();
  for (int s = 256; s > 0; s >>= 1){ if (tid < s) red[tid] = fminf(red[tid], red[tid+s]); __syncthreads(); }
  float r = red[0]; __syncthreads(); return r;
}
__device__ __forceinline__ float bred_sum(float v, float* red, int tid){
  red[tid] = v; __syncthreads();
  for (int s = 256; s > 0; s >>= 1){ if (tid < s) red[tid] += red[tid+s]; __syncthreads(); }
  float r = red[0]; __syncthreads(); return r;
}

// ---------------------------------------------------------------- scores
template<bool M8>
__device__ void scores_body(const float* sim, const void* tmask, const void* cmask,
                            float* tgts, float* diss, float* bgds,
                            float* srt, float* cum, float* red)
{
  int b = blockIdx.x, tid = threadIdx.x;
  bool valid = tid < NL;
  float sv = valid ? sim[(size_t)b*NL + tid] : 0.f;
  bool mk = false;
  if (valid){
    if constexpr (M8)
      mk = (tid < NLT) ? (((const u8*)tmask)[b*NLT + tid] != 0)
                       : (((const u8*)cmask)[b*NLC + tid - NLT] != 0);
    else
      mk = (tid < NLT) ? (((const int*)tmask)[b*NLT + tid] != 0)
                       : (((const int*)cmask)[b*NLC + tid - NLT] != 0);
  }
  float lt = (valid && mk) ? sv : NEGF;
  float m1 = bred_max(lt, red, tid);
  float e1 = valid ? expf(lt - m1) : 0.f;
  float s1 = bred_sum(e1, red, tid);
  if (valid) tgts[(size_t)b*NL + tid] = e1/s1;

  float bl = (valid && !mk) ? sv : NEGF;
  float m2 = bred_max(bl, red, tid);
  float e2 = valid ? expf(bl - m2) : 0.f;
  float s2 = bred_sum(e2, red, tid);
  float bg0 = e2/s2;

  srt[tid] = valid ? bg0 : INFINITY;
  __syncthreads();
  for (int k = 2; k <= 512; k <<= 1){
    for (int j = k >> 1; j > 0; j >>= 1){
      int ixj = tid ^ j;
      if (ixj > tid){
        float a = srt[tid], c = srt[ixj];
        if ((a > c) == ((tid & k) == 0)){ srt[tid] = c; srt[ixj] = a; }
      }
      __syncthreads();
    }
  }
  cum[tid] = srt[tid]; __syncthreads();
  for (int off = 1; off < 512; off <<= 1){
    float t = (tid >= off) ? cum[tid - off] : 0.f;
    __syncthreads();
    cum[tid] += t;
    __syncthreads();
  }
  float cand = (cum[tid] < 0.25f) ? 1.0f : srt[tid];
  float thr = bred_min(cand, red, tid);

  bool dm = valid && (bg0 >= thr);
  float dl = dm ? bl : NEGF;
  float l2 = dm ? NEGF : bl;
  float m3 = bred_max(dl, red, tid);
  float e3 = valid ? expf(dl - m3) : 0.f;
  float s3 = bred_sum(e3, red, tid);
  if (valid) diss[(size_t)b*NL + tid] = e3/s3;
  float m4 = bred_max(l2, red, tid);
  float e4 = valid ? expf(l2 - m4) : 0.f;
  float s4 = bred_sum(e4, red, tid);
  if (valid) bgds[(size_t)b*NL + tid] = e4/s4;
}
__global__ __launch_bounds__(512) void k_scores(const int* flags, const float* sim,
    const void* tmask, const void* cmask, float* tgts, float* diss, float* bgds){
  __shared__ float srt[512];
  __shared__ float cum[512];
  __shared__ float red[512];
  if (flags[1]) scores_body<true >(sim, tmask, cmask, tgts, diss, bgds, srt, cum, red);
  else          scores_body<false>(sim, tmask, cmask, tgts, diss, bgds, srt, cum, red);
}

// ---------------------------------------------------------------- tokens + src0
// grid (NB, 3), 128 threads; thread handles one float2 column pair.
template<bool BF>
__device__ void tokens_body(const void* tem, const void* ctx, const void* cls, const void* qe,
                            const float* __restrict__ tgts, const float* __restrict__ diss,
                            const float* __restrict__ bgds, float* src0)
{
  int b = blockIdx.x, dc = blockIdx.y, t = threadIdx.x;
  int e = dc*128 + t;                       // float2 index 0..383
  float a00=0,a01=0,a10=0,a11=0,a20=0,a21=0;
  const float* wt = tgts + (size_t)b*NL;
  const float* wd = diss + (size_t)b*NL;
  const float* wb = bgds + (size_t)b*NL;
  #pragma unroll 4
  for (int l = 0; l < NL; l++){
    float f0, f1;
    if constexpr (BF){
      const u16* row = (l < NLT) ? ((const u16*)tem + ((size_t)b*NLT + l)*ND)
                                 : ((const u16*)ctx + ((size_t)b*NLC + (l-NLT))*ND);
      u32 v = ((const u32*)row)[e];
      f0 = b2f((u16)(v & 0xffff)); f1 = b2f((u16)(v >> 16));
    } else {
      const float* row = (l < NLT) ? ((const float*)tem + ((size_t)b*NLT + l)*ND)
                                   : ((const float*)ctx + ((size_t)b*NLC + (l-NLT))*ND);
      float2 v = ((const float2*)row)[e];
      f0 = v.x; f1 = v.y;
    }
    float w0 = wt[l], w1 = wd[l], w2 = wb[l];  // wave-uniform -> s_load
    a00 = fmaf(w0,f0,a00); a01 = fmaf(w0,f1,a01);
    a10 = fmaf(w1,f0,a10); a11 = fmaf(w1,f1,a11);
    a20 = fmaf(w2,f0,a20); a21 = fmaf(w2,f1,a21);
  }
  int d0 = e*2, d1 = d0 + 1;
  float c0 = ldf<BF>(cls, (size_t)b*ND + d0), c1 = ldf<BF>(cls, (size_t)b*ND + d1);
  size_t base = (size_t)b*3*ND;
  src0[base        + d0] = a00 + ldf<BF>(qe, 0*ND + d0) + c0;
  src0[base        + d1] = a01 + ldf<BF>(qe, 0*ND + d1) + c1;
  src0[base +   ND + d0] = a10 + ldf<BF>(qe, 1*ND + d0);
  src0[base +   ND + d1] = a11 + ldf<BF>(qe, 1*ND + d1);
  src0[base + 2*ND + d0] = a20 + ldf<BF>(qe, 2*ND + d0);
  src0[base + 2*ND + d1] = a21 + ldf<BF>(qe, 2*ND + d1);
}
__global__ __launch_bounds__(128) void k_tokens(const int* flags, const void* tem,
    const void* ctx, const void* cls, const void* qe,
    const float* tgts, const float* diss, const float* bgds, float* src0){
  if (flags[0]) tokens_body<true >(tem, ctx, cls, qe, tgts, diss, bgds, src0);
  else          tokens_body<false>(tem, ctx, cls, qe, tgts, diss, bgds, src0);
}

// ---------------------------------------------------------------- GEMM partial
// C_part[ks][384][N] = A[:, ks*KC:(ks+1)*KC] @ W[ks*KC:(ks+1)*KC, :]
// block: 256 threads, one output column each, 16-row tile. No LDS, no barriers.
// A rows are wave-uniform -> scalar loads.
template<bool BF>
__device__ void gemm_part_body(const float* __restrict__ A, const void* __restrict__ W,
                               float* __restrict__ part, int K, int N, int KC)
{
  int n  = blockIdx.x*256 + threadIdx.x;
  int m0 = blockIdx.y*16;
  int ks = blockIdx.z;
  float acc[16];
  #pragma unroll
  for (int i = 0; i < 16; i++) acc[i] = 0.f;
  const float* Arow = A + (size_t)m0*K + (size_t)ks*KC;
  for (int kk = 0; kk < KC; kk += 4){
    size_t kg = (size_t)(ks*KC + kk);
    float w0 = ldf<BF>(W, (kg+0)*N + n);
    float w1 = ldf<BF>(W, (kg+1)*N + n);
    float w2 = ldf<BF>(W, (kg+2)*N + n);
    float w3 = ldf<BF>(W, (kg+3)*N + n);
    #pragma unroll
    for (int i = 0; i < 16; i++){
      float4 av = *(const float4*)(Arow + (size_t)i*K + kk);   // uniform -> s_load_dwordx4
      acc[i] = fmaf(av.x, w0, fmaf(av.y, w1, fmaf(av.z, w2, fmaf(av.w, w3, acc[i]))));
    }
  }
  float* po = part + (size_t)ks*384*N + (size_t)m0*N + n;
  #pragma unroll
  for (int i = 0; i < 16; i++) po[(size_t)i*N] = acc[i];
}
__global__ __launch_bounds__(256) void k_gemm_part(const int* flags, const float* A,
    const void* W, float* part, int K, int N, int KC){
  if (flags[0]) gemm_part_body<true >(A, W, part, K, N, KC);
  else          gemm_part_body<false>(A, W, part, K, N, KC);
}

// ---------------------------------------------------------------- fc1 epilogue: sum 2 partials + bias + GELU -> h
template<bool BF>
__device__ void fc1_fin_body(const float* __restrict__ p, const void* b1, float* __restrict__ h){
  int idx = (blockIdx.x*256 + threadIdx.x)*4;
  int n = idx % NH;
  float4 x0 = *(const float4*)(p + idx);
  float4 x1 = *(const float4*)(p + (size_t)384*NH + idx);
  float v[4] = {x0.x+x1.x, x0.y+x1.y, x0.z+x1.z, x0.w+x1.w};
  float4 o;
  float* op = &o.x;
  #pragma unroll
  for (int j = 0; j < 4; j++){
    float x = v[j] + ldf<BF>(b1, n + j);
    op[j] = 0.5f*x*(1.0f + erff(x*0.70710678118654752f));
  }
  *(float4*)(h + idx) = o;
}
__global__ __launch_bounds__(256) void k_fc1_fin(const int* flags, const float* p,
    const void* b1, float* h){
  if (flags[0]) fc1_fin_body<true >(p, b1, h);
  else          fc1_fin_body<false>(p, b1, h);
}

// ---------------------------------------------------------------- fc2 epilogue: sum 8 partials + bias + residual + flag select
template<bool BF>
__device__ void fc2_fin_body(const float* __restrict__ p, const void* b2,
                             const float* __restrict__ src0, const void* cls,
                             const void* qe, const int* flag, void* out){
  int idx = (blockIdx.x*256 + threadIdx.x)*4;
  int r = idx / ND;                 // row 0..383 (same for all 4 elems)
  int n = idx % ND;
  float s[4] = {0,0,0,0};
  #pragma unroll
  for (int ksp = 0; ksp < 8; ksp++){
    float4 v = *(const float4*)(p + (size_t)ksp*384*ND + idx);
    s[0]+=v.x; s[1]+=v.y; s[2]+=v.z; s[3]+=v.w;
  }
  float4 res = *(const float4*)(src0 + idx);
  const float* rp = &res.x;
  int bi = r/3, j = r - bi*3;
  bool take_src_ = (flag[bi] == 1);
  #pragma unroll
  for (int jj = 0; jj < 4; jj++){
    float val = s[jj] + ldf<BF>(b2, n + jj) + rp[jj];
    if (take_src_){
      val = ldf<BF>(qe, (size_t)j*ND + n + jj)
          + ((j == 0) ? ldf<BF>(cls, (size_t)bi*ND + n + jj) : 0.f);
    }
    if (false) {}
    s[jj] = val;
  }
  if (((const int*)flag) != nullptr){}
  // store per output dtype (follows input float dtype)
  extern __shared__ int _dummy[];
  (void)_dummy;
  if (BF){
    u16* o = (u16*)out;
    #pragma unroll
    for (int jj = 0; jj < 4; jj++) o[idx + jj] = f2b(s[jj]);
  } else {
    float4 o = {s[0], s[1], s[2], s[3]};
    *(float4*)((float*)out + idx) = o;
  }
}
__global__ __launch_bounds__(256) void k_fc2_fin(const int* flags, const float* p,
    const void* b2, const float* src0, const void* cls, const void* qe,
    const int* flag, void* out){
  if (flags[0]) fc2_fin_body<true >(p, b2, src0, cls, qe, flag, out);
  else          fc2_fin_body<false>(p, b2, src0, cls, qe, flag, out);
}

// ---------------------------------------------------------------- launch
extern "C" void kernel_launch(void* const* d_in, const int* in_sizes, int n_in,
                              void* d_out, int out_size, void* d_ws, size_t ws_size,
                              hipStream_t stream)
{
  const void* tem   = d_in[0];
  const void* tmask = d_in[1];
  const void* ctx   = d_in[2];
  const void* cmask = d_in[3];
  const void* cls   = d_in[4];
  const int*  flag  = (const int*)d_in[5];
  const void* qe    = d_in[6];
  const void* ls    = d_in[7];
  const void* w1    = d_in[8];
  const void* b1    = d_in[9];
  const void* w2    = d_in[10];
  const void* b2    = d_in[11];

  int*   flags = (int*)d_ws;
  float* W     = (float*)d_ws + 16;
  float* sim   = W;                                   // 128*464
  float* tgts  = sim  + (size_t)NB*NL;
  float* diss  = tgts + (size_t)NB*NL;
  float* bgds  = diss + (size_t)NB*NL;
  float* src0  = bgds + (size_t)NB*NL;                // 384*768
  float* h     = src0 + (size_t)384*ND;               // 384*3072
  float* pbuf  = h    + (size_t)384*NH;               // max(2*384*3072, 8*384*768) = 2359296

  hipLaunchKernelGGL(k_detect,  dim3(1), dim3(64), 0, stream, tem, tmask, flags);
  hipLaunchKernelGGL(k_sim,     dim3(NB, 29), dim3(256), 0, stream, flags, tem, ctx, cls, ls, sim);
  hipLaunchKernelGGL(k_scores,  dim3(NB), dim3(512), 0, stream, flags, sim, tmask, cmask, tgts, diss, bgds);
  hipLaunchKernelGGL(k_tokens,  dim3(NB, 3), dim3(128), 0, stream, flags, tem, ctx, cls, qe, tgts, diss, bgds, src0);
  // fc1: [384,768] @ [768,3072], split-K=2
  hipLaunchKernelGGL(k_gemm_part, dim3(NH/256, 384/16, 2), dim3(256), 0, stream,
                     flags, src0, w1, pbuf, ND, NH, ND/2);
  hipLaunchKernelGGL(k_fc1_fin, dim3(384*NH/1024), dim3(256), 0, stream, flags, pbuf, b1, h);
  // fc2: [384,3072] @ [3072,768], split-K=8
  hipLaunchKernelGGL(k_gemm_part, dim3(ND/256, 384/16, 8), dim3(256), 0, stream,
                     flags, h, w2, pbuf, NH, ND, NH/8);
  hipLaunchKernelGGL(k_fc2_fin, dim3(384*ND/1024), dim3(256), 0, stream,
                     flags, pbuf, b2, src0, cls, qe, flag, d_out);
}

// Round 3
// 139.085 us; speedup vs baseline: 5.2454x; 2.3966x over previous
//
#include <hip/hip_runtime.h>
#include <hip/hip_bf16.h>
#include <math.h>

typedef unsigned short u16;
typedef unsigned int   u32;
typedef unsigned char  u8;

#define NB  128
#define NLT 64
#define NLC 400
#define NL  464
#define ND  768
#define NH  3072
#define NEGF (-1e20f)

typedef __attribute__((ext_vector_type(8))) short bf16x8;
typedef __attribute__((ext_vector_type(4))) float f32x4;

__device__ __forceinline__ float b2f(u16 u){ return __uint_as_float(((u32)u)<<16); }
__device__ __forceinline__ u16 f2b(float f){
  u32 x = __float_as_uint(f);
  x += 0x7fffu + ((x>>16)&1u);
  return (u16)(x>>16);
}
template<bool BF> __device__ __forceinline__ float ldf(const void* p, size_t i){
  if constexpr (BF) return b2f(((const u16*)p)[i]);
  else              return ((const float*)p)[i];
}

// ---------------------------------------------------------------- ABI detect
__global__ void k_detect(const void* tem, const void* tmask, int* flags){
  int t = threadIdx.x;                     // 64 threads
  const u16* p = (const u16*)tem;
  float acc = 0.f;
  for (int i = t; i < 512; i += 64){
    float v = fabsf(b2f(p[i]));
    v = fminf(v, 1e10f);
    acc += v;
  }
  for (int off = 32; off; off >>= 1) acc += __shfl_down(acc, off);
  const u8* mb = (const u8*)tmask;
  int nz = 0;
  for (int i = t; i < 400; i += 64) if ((i & 3) != 0 && mb[i] != 0) nz = 1;
  unsigned long long anym = __ballot(nz);
  if (t == 0){
    flags[0] = (acc < 1e4f) ? 1 : 0;       // bf16 data vs f32-seen-as-bf16
    flags[1] = anym ? 1 : 0;               // byte-mask vs int32-mask
  }
}

// ---------------------------------------------------------------- sim logits
template<bool BF>
__device__ void sim_body(const void* tem, const void* ctx, const void* cls,
                         const void* lsp, float* sim,
                         float* clsf, float* red4, float* cnorm)
{
  int b = blockIdx.x, tile = blockIdx.y, tid = threadIdx.x;
  for (int i = tid; i < ND; i += 256) clsf[i] = ldf<BF>(cls, (size_t)b*ND + i);
  __syncthreads();
  float ss = 0.f;
  for (int i = tid; i < ND; i += 256) ss += clsf[i]*clsf[i];
  for (int off = 32; off; off >>= 1) ss += __shfl_down(ss, off);
  if ((tid & 63) == 0) red4[tid >> 6] = ss;
  __syncthreads();
  if (tid == 0) *cnorm = fmaxf(sqrtf(red4[0]+red4[1]+red4[2]+red4[3]), 1e-12f);
  __syncthreads();
  float cn = *cnorm;
  float escale = expf(ldf<BF>(lsp, 0));
  int lane = tid & 63, w = tid >> 6;
  float creg[12];
  #pragma unroll
  for (int j = 0; j < 12; j++) creg[j] = clsf[lane*12 + j];

  for (int rr = 0; rr < 4; rr++){
    int l = tile*16 + w + rr*4;
    float v[12];
    if constexpr (BF){
      const u16* row = (l < NLT) ? ((const u16*)tem + ((size_t)b*NLT + l)*ND)
                                 : ((const u16*)ctx + ((size_t)b*NLC + (l-NLT))*ND);
      const ushort4* rp = (const ushort4*)(row + lane*12);
      #pragma unroll
      for (int q = 0; q < 3; q++){
        ushort4 u = rp[q];
        v[q*4+0]=b2f(u.x); v[q*4+1]=b2f(u.y); v[q*4+2]=b2f(u.z); v[q*4+3]=b2f(u.w);
      }
    } else {
      const float* row = (l < NLT) ? ((const float*)tem + ((size_t)b*NLT + l)*ND)
                                   : ((const float*)ctx + ((size_t)b*NLC + (l-NLT))*ND);
      const float4* rp = (const float4*)(row + lane*12);
      #pragma unroll
      for (int q = 0; q < 3; q++){
        float4 u = rp[q];
        v[q*4+0]=u.x; v[q*4+1]=u.y; v[q*4+2]=u.z; v[q*4+3]=u.w;
      }
    }
    float dot = 0.f, rs = 0.f;
    #pragma unroll
    for (int j = 0; j < 12; j++){ dot += creg[j]*v[j]; rs += v[j]*v[j]; }
    for (int off = 32; off; off >>= 1){
      dot += __shfl_down(dot, off); rs += __shfl_down(rs, off);
    }
    if (lane == 0){
      float rn = fmaxf(sqrtf(rs), 1e-12f);
      sim[(size_t)b*NL + l] = dot / (cn*rn) * escale;
    }
  }
}
__global__ __launch_bounds__(256) void k_sim(const int* flags, const void* tem,
    const void* ctx, const void* cls, const void* lsp, float* sim){
  __shared__ float clsf[ND];
  __shared__ float red4[4];
  __shared__ float cnorm;
  if (flags[0]) sim_body<true >(tem, ctx, cls, lsp, sim, clsf, red4, &cnorm);
  else          sim_body<false>(tem, ctx, cls, lsp, sim, clsf, red4, &cnorm);
}

// ---------------------------------------------------------------- reductions
__device__ __forceinline__ float bred_max(float v, float* red, int tid){
  red[tid] = v; __syncthreads();
  for (int s = 256; s > 0; s >>= 1){ if (tid < s) red[tid] = fmaxf(red[tid], red[tid+s]); __syncthreads(); }
  float r = red[0]; __syncthreads(); return r;
}
__device__ __forceinline__ float bred_min(float v, float* red, int tid){
  red[tid] = v; __syncthreads();
  for (int s = 256; s > 0; s >>= 1){ if (tid < s) red[tid] = fminf(red[tid], red[tid+s]); __syncthreads(); }
  float r = red[0]; __syncthreads(); return r;
}
__device__ __forceinline__ float bred_sum(float v, float* red, int tid){
  red[tid] = v; __syncthreads();
  for (int s = 256; s > 0; s >>= 1){ if (tid < s) red[tid] += red[tid+s]; __syncthreads(); }
  float r = red[0]; __syncthreads(); return r;
}

// ---------------------------------------------------------------- scores
template<bool M8>
__device__ void scores_body(const float* sim, const void* tmask, const void* cmask,
                            float* tgts, float* diss, float* bgds,
                            float* srt, float* cum, float* red)
{
  int b = blockIdx.x, tid = threadIdx.x;
  bool valid = tid < NL;
  float sv = valid ? sim[(size_t)b*NL + tid] : 0.f;
  bool mk = false;
  if (valid){
    if constexpr (M8)
      mk = (tid < NLT) ? (((const u8*)tmask)[b*NLT + tid] != 0)
                       : (((const u8*)cmask)[b*NLC + tid - NLT] != 0);
    else
      mk = (tid < NLT) ? (((const int*)tmask)[b*NLT + tid] != 0)
                       : (((const int*)cmask)[b*NLC + tid - NLT] != 0);
  }
  float lt = (valid && mk) ? sv : NEGF;
  float m1 = bred_max(lt, red, tid);
  float e1 = valid ? expf(lt - m1) : 0.f;
  float s1 = bred_sum(e1, red, tid);
  if (valid) tgts[(size_t)b*NL + tid] = e1/s1;

  float bl = (valid && !mk) ? sv : NEGF;
  float m2 = bred_max(bl, red, tid);
  float e2 = valid ? expf(bl - m2) : 0.f;
  float s2 = bred_sum(e2, red, tid);
  float bg0 = e2/s2;

  srt[tid] = valid ? bg0 : INFINITY;
  __syncthreads();
  for (int k = 2; k <= 512; k <<= 1){
    for (int j = k >> 1; j > 0; j >>= 1){
      int ixj = tid ^ j;
      if (ixj > tid){
        float a = srt[tid], c = srt[ixj];
        if ((a > c) == ((tid & k) == 0)){ srt[tid] = c; srt[ixj] = a; }
      }
      __syncthreads();
    }
  }
  cum[tid] = srt[tid]; __syncthreads();
  for (int off = 1; off < 512; off <<= 1){
    float t = (tid >= off) ? cum[tid - off] : 0.f;
    __syncthreads();
    cum[tid] += t;
    __syncthreads();
  }
  float cand = (cum[tid] < 0.25f) ? 1.0f : srt[tid];
  float thr = bred_min(cand, red, tid);

  bool dm = valid && (bg0 >= thr);
  float dl = dm ? bl : NEGF;
  float l2 = dm ? NEGF : bl;
  float m3 = bred_max(dl, red, tid);
  float e3 = valid ? expf(dl - m3) : 0.f;
  float s3 = bred_sum(e3, red, tid);
  if (valid) diss[(size_t)b*NL + tid] = e3/s3;
  float m4 = bred_max(l2, red, tid);
  float e4 = valid ? expf(l2 - m4) : 0.f;
  float s4 = bred_sum(e4, red, tid);
  if (valid) bgds[(size_t)b*NL + tid] = e4/s4;
}
__global__ __launch_bounds__(512) void k_scores(const int* flags, const float* sim,
    const void* tmask, const void* cmask, float* tgts, float* diss, float* bgds){
  __shared__ float srt[512];
  __shared__ float cum[512];
  __shared__ float red[512];
  if (flags[1]) scores_body<true >(sim, tmask, cmask, tgts, diss, bgds, srt, cum, red);
  else          scores_body<false>(sim, tmask, cmask, tgts, diss, bgds, srt, cum, red);
}

// ---------------------------------------------------------------- tokens (L-split partials)
// grid (NB, 3, 2), 128 threads; thread = one float2 column pair, z = L-chunk.
template<bool BF>
__device__ void tokens_body(const void* tem, const void* ctx,
                            const float* __restrict__ tgts, const float* __restrict__ diss,
                            const float* __restrict__ bgds, float* tokp)
{
  int b = blockIdx.x, dc = blockIdx.y, z = blockIdx.z, t = threadIdx.x;
  int e = dc*128 + t;                       // float2 index 0..383
  int l0 = z*232, l1 = l0 + 232;
  float a00=0,a01=0,a10=0,a11=0,a20=0,a21=0;
  const float* wt = tgts + (size_t)b*NL;
  const float* wd = diss + (size_t)b*NL;
  const float* wb = bgds + (size_t)b*NL;
  #pragma unroll 4
  for (int l = l0; l < l1; l++){
    float f0, f1;
    if constexpr (BF){
      const u16* row = (l < NLT) ? ((const u16*)tem + ((size_t)b*NLT + l)*ND)
                                 : ((const u16*)ctx + ((size_t)b*NLC + (l-NLT))*ND);
      u32 v = ((const u32*)row)[e];
      f0 = b2f((u16)(v & 0xffff)); f1 = b2f((u16)(v >> 16));
    } else {
      const float* row = (l < NLT) ? ((const float*)tem + ((size_t)b*NLT + l)*ND)
                                   : ((const float*)ctx + ((size_t)b*NLC + (l-NLT))*ND);
      float2 v = ((const float2*)row)[e];
      f0 = v.x; f1 = v.y;
    }
    float w0 = wt[l], w1 = wd[l], w2 = wb[l];  // wave-uniform -> s_load
    a00 = fmaf(w0,f0,a00); a01 = fmaf(w0,f1,a01);
    a10 = fmaf(w1,f0,a10); a11 = fmaf(w1,f1,a11);
    a20 = fmaf(w2,f0,a20); a21 = fmaf(w2,f1,a21);
  }
  int d0 = e*2, d1 = d0 + 1;
  float* base = tokp + (size_t)z*(384*ND) + (size_t)b*3*ND;
  base[0*ND + d0] = a00; base[0*ND + d1] = a01;
  base[1*ND + d0] = a10; base[1*ND + d1] = a11;
  base[2*ND + d0] = a20; base[2*ND + d1] = a21;
}
__global__ __launch_bounds__(128) void k_tokens(const int* flags, const void* tem,
    const void* ctx, const float* tgts, const float* diss, const float* bgds, float* tokp){
  if (flags[0]) tokens_body<true >(tem, ctx, tgts, diss, bgds, tokp);
  else          tokens_body<false>(tem, ctx, tgts, diss, bgds, tokp);
}

// ---------------------------------------------------------------- src0 = partials + qe + cls  (f32 + bf16 copies)
template<bool BF>
__device__ void src0_body(const float* __restrict__ tokp, const void* cls, const void* qe,
                          float* __restrict__ src0f, u16* __restrict__ src0b){
  int idx = (blockIdx.x*256 + threadIdx.x)*4;   // over 384*768
  int r = idx / ND, n = idx % ND;
  int b = r/3, j = r - b*3;
  float4 t0 = *(const float4*)(tokp + idx);
  float4 t1 = *(const float4*)(tokp + 384*ND + idx);
  float v[4] = {t0.x+t1.x, t0.y+t1.y, t0.z+t1.z, t0.w+t1.w};
  ushort4 ob;
  u16* obp = &ob.x;
  float4 of;
  float* ofp = &of.x;
  #pragma unroll
  for (int q = 0; q < 4; q++){
    float x = v[q] + ldf<BF>(qe, (size_t)j*ND + n + q);
    if (j == 0) x += ldf<BF>(cls, (size_t)b*ND + n + q);
    ofp[q] = x;
    obp[q] = f2b(x);
  }
  *(float4*)(src0f + idx) = of;
  *(ushort4*)(src0b + idx) = ob;
}
__global__ __launch_bounds__(256) void k_src0(const int* flags, const float* tokp,
    const void* cls, const void* qe, float* src0f, u16* src0b){
  if (flags[0]) src0_body<true >(tokp, cls, qe, src0f, src0b);
  else          src0_body<false>(tokp, cls, qe, src0f, src0b);
}

// ---------------------------------------------------------------- MFMA GEMM core
// C[64x64] tile = A[M,K](bf16, row-major) @ W[K,N] (bf16 or f32, converted on stage).
// 256 thr = 4 waves (2x2 of 32x32), mfma_f32_16x16x32_bf16.
// LDS: As 8KB [row64][k64] + Bs 8KB [col64][k64], both XOR-swizzled byte^=((row&7)<<4).
template<bool BFW>
__device__ __forceinline__ void mfma_loop(const u16* __restrict__ Abf, const void* __restrict__ Wt,
                                          int K, int N, int m0, int n0, int kb_, int ke_,
                                          u16* lds, f32x4 (&acc)[2][2])
{
  int tid = threadIdx.x, lane = tid & 63;
  int w = tid >> 6, wr = w >> 1, wc = w & 1;
  #pragma unroll
  for (int i = 0; i < 2; i++)
    #pragma unroll
    for (int j = 0; j < 2; j++) acc[i][j] = (f32x4){0.f,0.f,0.f,0.f};

  int rA = tid >> 2, kcA = (tid & 3) * 16;          // A stage: 32B per thread
  int cB = tid & 63, kbB = (tid >> 6) * 16;         // B stage: 16 elems per thread

  for (int k0 = kb_; k0 < ke_; k0 += 64){
    __syncthreads();
    // stage A tile (bf16 source)
    {
      const uint4* srcA = (const uint4*)(Abf + (size_t)(m0 + rA)*K + k0 + kcA);
      uint4 a0 = srcA[0], a1 = srcA[1];
      u32 sw = (u32)((rA & 7) << 4);
      u32 ba = (u32)(rA*128 + kcA*2);
      *(uint4*)((char*)lds + (ba ^ sw)) = a0;
      *(uint4*)((char*)lds + ((ba + 16) ^ sw)) = a1;
    }
    // stage B tile transposed: Bs[col][k]
    {
      size_t wbase = (size_t)(k0 + kbB)*N + n0 + cB;
      u32 sw = (u32)((cB & 7) << 4);
      #pragma unroll
      for (int q = 0; q < 16; q++){
        u16 wv;
        if constexpr (BFW) wv = ((const u16*)Wt)[wbase + (size_t)q*N];
        else               wv = f2b(((const float*)Wt)[wbase + (size_t)q*N]);
        u32 bb = (u32)(cB*128 + (kbB + q)*2) ^ sw;
        *((u16*)((char*)lds + 8192 + bb)) = wv;
      }
    }
    __syncthreads();
    #pragma unroll
    for (int kb = 0; kb < 2; kb++){
      bf16x8 af[2], bfr[2];
      #pragma unroll
      for (int i = 0; i < 2; i++){
        int ml = wr*32 + i*16 + (lane & 15);
        u32 ab = (u32)(ml*128 + kb*64 + (lane >> 4)*16) ^ (u32)((ml & 7) << 4);
        af[i] = *(const bf16x8*)((char*)lds + ab);
        int cl = wc*32 + i*16 + (lane & 15);
        u32 bb = (u32)(cl*128 + kb*64 + (lane >> 4)*16) ^ (u32)((cl & 7) << 4);
        bfr[i] = *(const bf16x8*)((char*)lds + 8192 + bb);
      }
      #pragma unroll
      for (int i = 0; i < 2; i++)
        #pragma unroll
        for (int j = 0; j < 2; j++)
          acc[i][j] = __builtin_amdgcn_mfma_f32_16x16x32_bf16(af[i], bfr[j], acc[i][j], 0, 0, 0);
    }
  }
}

// fc1: h = gelu(src0b @ w1 + b1), bf16 out. grid (NH/64, 384/64)
template<bool BFW>
__device__ void fc1_mf_body(const u16* src0b, const void* w1, const void* b1, u16* hbf, u16* lds){
  int n0 = blockIdx.x*64, m0 = blockIdx.y*64;
  f32x4 acc[2][2];
  mfma_loop<BFW>(src0b, w1, ND, NH, m0, n0, 0, ND, lds, acc);
  int lane = threadIdx.x & 63, w = threadIdx.x >> 6, wr = w >> 1, wc = w & 1;
  #pragma unroll
  for (int j = 0; j < 2; j++){
    int n = n0 + wc*32 + j*16 + (lane & 15);
    float bb = ldf<BFW>(b1, n);
    #pragma unroll
    for (int i = 0; i < 2; i++){
      int mb = m0 + wr*32 + i*16 + (lane >> 4)*4;
      #pragma unroll
      for (int r = 0; r < 4; r++){
        float x = acc[i][j][r] + bb;
        float g = 0.5f*x*(1.0f + erff(x*0.70710678118654752f));
        hbf[(size_t)(mb + r)*NH + n] = f2b(g);
      }
    }
  }
}
__global__ __launch_bounds__(256) void k_fc1_mf(const int* flags, const u16* src0b,
    const void* w1, const void* b1, u16* hbf){
  __shared__ u16 lds[8192];
  if (flags[0]) fc1_mf_body<true >(src0b, w1, b1, hbf, lds);
  else          fc1_mf_body<false>(src0b, w1, b1, hbf, lds);
}

// fc2 partials: fc2p[z] = hbf[:, z*768:(z+1)*768] @ w2[z*768:(z+1)*768, :]. grid (ND/64, 384/64, 4)
template<bool BFW>
__device__ void fc2_mf_body(const u16* hbf, const void* w2, float* fc2p, u16* lds){
  int n0 = blockIdx.x*64, m0 = blockIdx.y*64, z = blockIdx.z;
  f32x4 acc[2][2];
  mfma_loop<BFW>(hbf, w2, NH, ND, m0, n0, z*768, (z+1)*768, lds, acc);
  int lane = threadIdx.x & 63, w = threadIdx.x >> 6, wr = w >> 1, wc = w & 1;
  float* po = fc2p + (size_t)z*(384*ND);
  #pragma unroll
  for (int j = 0; j < 2; j++){
    int n = n0 + wc*32 + j*16 + (lane & 15);
    #pragma unroll
    for (int i = 0; i < 2; i++){
      int mb = m0 + wr*32 + i*16 + (lane >> 4)*4;
      #pragma unroll
      for (int r = 0; r < 4; r++)
        po[(size_t)(mb + r)*ND + n] = acc[i][j][r];
    }
  }
}
__global__ __launch_bounds__(256) void k_fc2_mf(const int* flags, const u16* hbf,
    const void* w2, float* fc2p, u16* lds_unused){
  __shared__ u16 lds[8192];
  if (flags[0]) fc2_mf_body<true >(hbf, w2, fc2p, lds);
  else          fc2_mf_body<false>(hbf, w2, fc2p, lds);
}

// ---------------------------------------------------------------- fc2 epilogue: sum 4 partials + bias + residual + flag select
template<bool BF>
__device__ void fc2_fin_body(const float* __restrict__ p, const void* b2,
                             const float* __restrict__ src0f, const void* cls,
                             const void* qe, const int* flag, void* out){
  int idx = (blockIdx.x*256 + threadIdx.x)*4;
  int r = idx / ND;
  int n = idx % ND;
  float s[4] = {0,0,0,0};
  #pragma unroll
  for (int ksp = 0; ksp < 4; ksp++){
    float4 v = *(const float4*)(p + (size_t)ksp*(384*ND) + idx);
    s[0]+=v.x; s[1]+=v.y; s[2]+=v.z; s[3]+=v.w;
  }
  float4 res = *(const float4*)(src0f + idx);
  const float* rp = &res.x;
  int bi = r/3, j = r - bi*3;
  bool take_src_ = (flag[bi] == 1);
  #pragma unroll
  for (int jj = 0; jj < 4; jj++){
    float val = s[jj] + ldf<BF>(b2, n + jj) + rp[jj];
    if (take_src_){
      val = ldf<BF>(qe, (size_t)j*ND + n + jj)
          + ((j == 0) ? ldf<BF>(cls, (size_t)bi*ND + n + jj) : 0.f);
    }
    s[jj] = val;
  }
  if constexpr (BF){
    ushort4 o = { f2b(s[0]), f2b(s[1]), f2b(s[2]), f2b(s[3]) };
    *(ushort4*)((u16*)out + idx) = o;
  } else {
    float4 o = {s[0], s[1], s[2], s[3]};
    *(float4*)((float*)out + idx) = o;
  }
}
__global__ __launch_bounds__(256) void k_fc2_fin(const int* flags, const float* p,
    const void* b2, const float* src0f, const void* cls, const void* qe,
    const int* flag, void* out){
  if (flags[0]) fc2_fin_body<true >(p, b2, src0f, cls, qe, flag, out);
  else          fc2_fin_body<false>(p, b2, src0f, cls, qe, flag, out);
}

// ---------------------------------------------------------------- launch
extern "C" void kernel_launch(void* const* d_in, const int* in_sizes, int n_in,
                              void* d_out, int out_size, void* d_ws, size_t ws_size,
                              hipStream_t stream)
{
  const void* tem   = d_in[0];
  const void* tmask = d_in[1];
  const void* ctx   = d_in[2];
  const void* cmask = d_in[3];
  const void* cls   = d_in[4];
  const int*  flag  = (const int*)d_in[5];
  const void* qe    = d_in[6];
  const void* ls    = d_in[7];
  const void* w1    = d_in[8];
  const void* b1    = d_in[9];
  const void* w2    = d_in[10];
  const void* b2    = d_in[11];

  int*   flags = (int*)d_ws;
  float* p     = (float*)d_ws + 16;
  float* sim   = p;  p += (size_t)NB*NL;            // 59392
  float* tgts  = p;  p += (size_t)NB*NL;
  float* diss  = p;  p += (size_t)NB*NL;
  float* bgds  = p;  p += (size_t)NB*NL;
  float* tokp  = p;  p += (size_t)2*384*ND;         // 589824
  float* src0f = p;  p += (size_t)384*ND;           // 294912
  u16*   src0b = (u16*)p; p += (size_t)384*ND/2;    // 294912 u16
  u16*   hbf   = (u16*)p; p += (size_t)384*NH/2;    // 1179648 u16
  float* fc2p  = p;  p += (size_t)4*384*ND;         // 1179648

  hipLaunchKernelGGL(k_detect,  dim3(1), dim3(64), 0, stream, tem, tmask, flags);
  hipLaunchKernelGGL(k_sim,     dim3(NB, 29), dim3(256), 0, stream, flags, tem, ctx, cls, ls, sim);
  hipLaunchKernelGGL(k_scores,  dim3(NB), dim3(512), 0, stream, flags, sim, tmask, cmask, tgts, diss, bgds);
  hipLaunchKernelGGL(k_tokens,  dim3(NB, 3, 2), dim3(128), 0, stream, flags, tem, ctx, tgts, diss, bgds, tokp);
  hipLaunchKernelGGL(k_src0,    dim3(384*ND/1024), dim3(256), 0, stream, flags, tokp, cls, qe, src0f, src0b);
  hipLaunchKernelGGL(k_fc1_mf,  dim3(NH/64, 384/64), dim3(256), 0, stream, flags, src0b, w1, b1, hbf);
  hipLaunchKernelGGL(k_fc2_mf,  dim3(ND/64, 384/64, 4), dim3(256), 0, stream, flags, hbf, w2, fc2p, (u16*)nullptr);
  hipLaunchKernelGGL(k_fc2_fin, dim3(384*ND/1024), dim3(256), 0, stream, flags, fc2p, b2, src0f, cls, qe, flag, d_out);
}